// Round 8
// baseline (385.237 us; speedup 1.0000x reference)
//
#include <hip/hip_runtime.h>
#include <cstdint>
#include <cmath>

#define THREADS 256
#define LDP 6016
#define RGROUPS 8
#define EDGE_R 64        // edge colsum rows per slab -> 94 slabs
#define TI 64            // node rows per strip
#define TJ 64            // node cols per tile
#define ASTR 68          // A-tile stride (floats): rows offset by 4 banks
#define ESTR 36          // emb-tile stride
#define CSTR 68          // colsum buf stride
#define BSTR 36          // epilogue buf stride

// ---------------- fused node pass: Pc = colsum partials, PH = partial A*emb ----
// grid (nch, strips, 2). Per 64x64 tile: stage A+E in LDS; colsum accumulated
// from staged registers (free); 4 waves each own 16 j-cols; thread (rg,lg)
// holds acc[4 rows = rg+16k][8 l = 8lg..].
__global__ void node_pass_kernel(const float* __restrict__ A0, const float* __restrict__ A1,
                                 const float* __restrict__ E0, const float* __restrict__ E1,
                                 float* __restrict__ Pc,   // [2][strips][LDP]
                                 float* __restrict__ PH,   // [2][nch][N][32]
                                 int N, int strips, int chunkW, int nch) {
    const int z = blockIdx.z;
    const float* __restrict__ A = z ? A1 : A0;
    const float* __restrict__ E = z ? E1 : E0;
    const int strip = blockIdx.y;
    const int r0 = strip * TI;
    const int rows = min(TI, N - r0);
    const int chunk = blockIdx.x;
    const int j0c = chunk * chunkW;
    const int j1c = min(j0c + chunkW, N);   // multiple of 4 (N%4==0, chunkW%64==0)

    __shared__ float At[TI * ASTR];   // 17408 B
    __shared__ float Et[TJ * ESTR];   //  9216 B
    __shared__ float cs[16 * CSTR];   //  4352 B

    const int t = threadIdx.x;
    const int rg = t & 15;
    const int lg = (t >> 4) & 3;
    const int jg = t >> 6;            // wave id

    float acc[4][8];
#pragma unroll
    for (int k = 0; k < 4; ++k)
#pragma unroll
        for (int u = 0; u < 8; ++u) acc[k][u] = 0.f;

    const int sr = t >> 4;            // staging row base (0..15)
    const int sc4 = t & 15;           // staging col group

    for (int jt = j0c; jt < j1c; jt += TJ) {
        // ---- stage A (4 float4/thread) + free colsum accumulate ----
        float csx = 0.f, csy = 0.f, csz = 0.f, csw = 0.f;
#pragma unroll
        for (int p = 0; p < 4; ++p) {
            int r = sr + 16 * p;
            int gj = jt + 4 * sc4;
            float4 v = {0.f, 0.f, 0.f, 0.f};
            if (r < rows && gj < j1c)
                v = *reinterpret_cast<const float4*>(&A[(size_t)(r0 + r) * N + gj]);
            *reinterpret_cast<float4*>(&At[r * ASTR + 4 * sc4]) = v;
            csx += v.x; csy += v.y; csz += v.z; csw += v.w;
        }
        {
            float4 c4v = {csx, csy, csz, csw};
            *reinterpret_cast<float4*>(&cs[sr * CSTR + 4 * sc4]) = c4v;
        }
        // ---- stage E (2 float4/thread) ----
#pragma unroll
        for (int p = 0; p < 2; ++p) {
            int f = t + p * THREADS;
            int jr = f >> 3;
            int l4 = (f & 7) << 2;
            int gj = jt + jr;
            float4 v = {0.f, 0.f, 0.f, 0.f};
            if (gj < j1c)
                v = *reinterpret_cast<const float4*>(&E[(size_t)gj * 32 + l4]);
            *reinterpret_cast<float4*>(&Et[jr * ESTR + l4]) = v;
        }
        __syncthreads();

        // ---- compute: wave jg owns j-cols [jg*16, jg*16+16) ----
#pragma unroll 4
        for (int jj = 0; jj < 16; ++jj) {
            const int jl = jg * 16 + jj;
            const float a0 = At[(rg +  0) * ASTR + jl];
            const float a1 = At[(rg + 16) * ASTR + jl];
            const float a2 = At[(rg + 32) * ASTR + jl];
            const float a3 = At[(rg + 48) * ASTR + jl];
            const float4 eA = *reinterpret_cast<const float4*>(&Et[jl * ESTR + 8 * lg]);
            const float4 eB = *reinterpret_cast<const float4*>(&Et[jl * ESTR + 8 * lg + 4]);
            const float e[8] = {eA.x, eA.y, eA.z, eA.w, eB.x, eB.y, eB.z, eB.w};
#pragma unroll
            for (int u = 0; u < 8; ++u) {
                acc[0][u] += a0 * e[u];
                acc[1][u] += a1 * e[u];
                acc[2][u] += a2 * e[u];
                acc[3][u] += a3 * e[u];
            }
        }
        // ---- colsum finalize (wave 0, overlaps compute) ----
        if (t < 64) {
            int gj = jt + t;
            if (gj < j1c) {
                float s = 0.f;
#pragma unroll
                for (int g = 0; g < 16; ++g) s += cs[g * CSTR + t];
                Pc[((size_t)z * strips + strip) * LDP + gj] = s;
            }
        }
        __syncthreads();
    }

    // ---- epilogue: reduce acc across 4 waves into buf[64][BSTR] (reuse At) ----
    float* buf = At;
    for (int s = 0; s < 4; ++s) {
        if (jg == s) {
#pragma unroll
            for (int k = 0; k < 4; ++k) {
                float* b = &buf[(rg + 16 * k) * BSTR + 8 * lg];
                if (s == 0) {
#pragma unroll
                    for (int u = 0; u < 8; ++u) b[u] = acc[k][u];
                } else {
#pragma unroll
                    for (int u = 0; u < 8; ++u) b[u] += acc[k][u];
                }
            }
        }
        __syncthreads();
    }
    {
        int rr = t >> 2;
        int l8 = (t & 3) * 8;
        if (rr < rows) {
            const float* b = &buf[rr * BSTR + l8];
            float4 v0 = {b[0], b[1], b[2], b[3]};
            float4 v1 = {b[4], b[5], b[6], b[7]};
            size_t off = ((size_t)(z * nch + chunk) * N + (r0 + rr)) * 32 + l8;
            *reinterpret_cast<float4*>(&PH[off]) = v0;
            *reinterpret_cast<float4*>(&PH[off + 4]) = v1;
        }
    }
}

// ---------------- edge colsum (unweighted, proven R6 structure) ----------------
__global__ __launch_bounds__(THREADS, 8)
void colsum_tile_kernel(const float* __restrict__ A0,
                        const float* __restrict__ A1,
                        float* __restrict__ P,
                        int N, int nSlabs, int R) {
    const int z = blockIdx.z;
    const float* __restrict__ A = z ? A1 : A0;
    const int col = blockIdx.x * (THREADS * 4) + threadIdx.x * 4;
    if (col >= N) return;
    const int slab = blockIdx.y;
    int r0 = slab * R;
    int r1 = r0 + R;
    if (r1 > N) r1 = N;

    float ax = 0.f, ay = 0.f, az = 0.f, aw = 0.f;
    float bx = 0.f, by = 0.f, bz = 0.f, bw = 0.f;
    const float* p = A + (size_t)r0 * N + col;
    const size_t sN = (size_t)N;
    int r = r0;
    for (; r + 8 <= r1; r += 8, p += 8 * sN) {
        float4 v0 = *reinterpret_cast<const float4*>(p + 0 * sN);
        float4 v1 = *reinterpret_cast<const float4*>(p + 1 * sN);
        float4 v2 = *reinterpret_cast<const float4*>(p + 2 * sN);
        float4 v3 = *reinterpret_cast<const float4*>(p + 3 * sN);
        float4 v4 = *reinterpret_cast<const float4*>(p + 4 * sN);
        float4 v5 = *reinterpret_cast<const float4*>(p + 5 * sN);
        float4 v6 = *reinterpret_cast<const float4*>(p + 6 * sN);
        float4 v7 = *reinterpret_cast<const float4*>(p + 7 * sN);
        ax += v0.x; ay += v0.y; az += v0.z; aw += v0.w;
        bx += v1.x; by += v1.y; bz += v1.z; bw += v1.w;
        ax += v2.x; ay += v2.y; az += v2.z; aw += v2.w;
        bx += v3.x; by += v3.y; bz += v3.z; bw += v3.w;
        ax += v4.x; ay += v4.y; az += v4.z; aw += v4.w;
        bx += v5.x; by += v5.y; bz += v5.z; bw += v5.w;
        ax += v6.x; ay += v6.y; az += v6.z; aw += v6.w;
        bx += v7.x; by += v7.y; bz += v7.z; bw += v7.w;
    }
    for (; r < r1; ++r, p += sN) {
        float4 v = *reinterpret_cast<const float4*>(p);
        ax += v.x; ay += v.y; az += v.z; aw += v.w;
    }
    float4 o = {ax + bx, ay + by, az + bz, aw + bw};
    *reinterpret_cast<float4*>(&P[((size_t)z * nSlabs + slab) * LDP + col]) = o;
}

// ---------------- reduce partials over slabs/strips ----------------
__global__ void reduce_atomic_kernel(const float* __restrict__ P,
                                     float* __restrict__ out0,
                                     float* __restrict__ out1,
                                     int N, int nSlabs) {
    int col = blockIdx.x * (THREADS * 4) + threadIdx.x * 4;
    if (col >= N) return;
    int z = blockIdx.y;
    int chunk = (nSlabs + RGROUPS - 1) / RGROUPS;
    int i0 = blockIdx.z * chunk;
    int i1 = i0 + chunk;
    if (i1 > nSlabs) i1 = nSlabs;
    float* out = z ? out1 : out0;

    const float* p = P + ((size_t)z * nSlabs + i0) * LDP + col;
    float4 s0 = {0, 0, 0, 0}, s1 = {0, 0, 0, 0};
    int i = i0;
    for (; i + 2 <= i1; i += 2, p += 2 * LDP) {
        float4 a = *reinterpret_cast<const float4*>(p);
        float4 b = *reinterpret_cast<const float4*>(p + LDP);
        s0.x += a.x; s0.y += a.y; s0.z += a.z; s0.w += a.w;
        s1.x += b.x; s1.y += b.y; s1.z += b.z; s1.w += b.w;
    }
    if (i < i1) {
        float4 a = *reinterpret_cast<const float4*>(p);
        s0.x += a.x; s0.y += a.y; s0.z += a.z; s0.w += a.w;
    }
    atomicAdd(&out[col + 0], s0.x + s1.x);
    atomicAdd(&out[col + 1], s0.y + s1.y);
    atomicAdd(&out[col + 2], s0.z + s1.z);
    atomicAdd(&out[col + 3], s0.w + s1.w);
}

// ---------------- merged tiny feature reductions (6 units) ----------------
__global__ void feat_all_kernel(const float* __restrict__ emb1, const float* __restrict__ emb2,
                                const float* __restrict__ eat1, const float* __restrict__ eat2,
                                const float* __restrict__ PH,
                                const float* __restrict__ c1, const float* __restrict__ c2,
                                const float* __restrict__ ce1, const float* __restrict__ ce2,
                                float* __restrict__ n1, float* __restrict__ n2,
                                float* __restrict__ eg1, float* __restrict__ eg2,
                                int Nn, int Ne, int nch) {
    int unit = blockIdx.y;
    const float* feat = nullptr; const float* w = nullptr; const float* ph = nullptr;
    float* outS = nullptr; float* outP = nullptr;
    int total, log2L;
    if (unit == 0)      { feat = emb1; w = c1;  outS = n1;  outP = n1 + 32;  total = Nn * 32; log2L = 5; }
    else if (unit == 1) { feat = emb2; w = c2;  outS = n2;  outP = n2 + 32;  total = Nn * 32; log2L = 5; }
    else if (unit == 2) { feat = eat1; w = ce1; outS = eg1; outP = eg1 + 16; total = Ne * 16; log2L = 4; }
    else if (unit == 3) { feat = eat2; w = ce2; outS = eg2; outP = eg2 + 16; total = Ne * 16; log2L = 4; }
    else if (unit == 4) { ph = PH;                              w = c1; outP = n1 + 64; total = Nn * 32; log2L = 5; }
    else                { ph = PH + (size_t)nch * Nn * 32;      w = c2; outP = n2 + 64; total = Nn * 32; log2L = 5; }

    int stride = gridDim.x * blockDim.x;
    int idx = blockIdx.x * blockDim.x + threadIdx.x;
    int L = 1 << log2L;
    int l = idx & (L - 1);
    float as = 0.f, ap = 0.f;
    if (ph) {
        for (int i = idx; i < total; i += stride) {
            float v = 0.f;
            for (int ch = 0; ch < nch; ++ch) v += ph[(size_t)ch * total + i];
            ap += w[i >> log2L] * v;
        }
    } else {
        for (int i = idx; i < total; i += stride) {
            float v = feat[i];
            as += v;
            ap += w[i >> log2L] * v;
        }
        atomicAdd(&outS[l], as);
    }
    atomicAdd(&outP[l], ap);
}

// ---------------- scoring ----------------
__global__ void scoring_kernel(const float* __restrict__ Wn,
                               const float* __restrict__ We,
                               const float* __restrict__ n1,
                               const float* __restrict__ n2,
                               const float* __restrict__ eg1,
                               const float* __restrict__ eg2,
                               float* __restrict__ scoring) {
    int b = blockIdx.y;
    int chunk = blockIdx.x;
    const float *W, *e1, *e2;
    int total, log2D;
    if (b < 3) {
        W = Wn + (size_t)b * (64 * 64 * 16);
        e1 = n1 + (b == 2 ? 32 : 0);
        e2 = n2 + (b == 2 ? 32 : 0);
        total = 64 * 64 * 16;
        log2D = 6;
    } else {
        W = We; e1 = eg1; e2 = eg2;
        total = 32 * 32 * 16;
        log2D = 5;
    }
    int begin = chunk * 4096 + threadIdx.x;
    int end = (chunk + 1) * 4096;
    if (end > total) end = total;
    float acc = 0.f;
    for (int idx = begin; idx < end; idx += 256) {
        int de = idx >> 4;
        int e = de & ((1 << log2D) - 1);
        int dd = de >> log2D;
        acc += e1[dd] * e2[e] * W[idx];
    }
    __shared__ float red[256];
    red[threadIdx.x] = acc;
    __syncthreads();
    if (threadIdx.x < 16) {
        float s = 0.f;
        for (int t = threadIdx.x; t < 256; t += 16) s += red[t];
        atomicAdd(&scoring[b * 16 + threadIdx.x], s);
    }
}

// ---------------- final MLP head ----------------
__global__ void final_kernel(const float* __restrict__ scoring,
                             const float* __restrict__ n1,
                             const float* __restrict__ n2,
                             const float* __restrict__ eg1,
                             const float* __restrict__ eg2,
                             const float* __restrict__ Wbn,
                             const float* __restrict__ bn,
                             const float* __restrict__ Wbe,
                             const float* __restrict__ be,
                             const float* __restrict__ m1w, const float* __restrict__ m1b,
                             const float* __restrict__ m2w, const float* __restrict__ m2b,
                             const float* __restrict__ m3w, const float* __restrict__ m3b,
                             const float* __restrict__ sw, const float* __restrict__ sb,
                             const float* __restrict__ avg_v,
                             float* __restrict__ out) {
    __shared__ float sval[4][16];
    __shared__ float scores[4];
    int t = threadIdx.x;
    int b = t >> 4, k = t & 15;

    float blk;
    if (b < 3) {
        const float* e1 = n1 + (b == 2 ? 32 : 0);
        const float* e2 = n2 + (b == 2 ? 32 : 0);
        const float* wb = Wbn + (size_t)b * (16 * 128) + k * 128;
        float s = 0.f;
        for (int j = 0; j < 64; ++j) s += wb[j] * e1[j];
        for (int j = 0; j < 64; ++j) s += wb[64 + j] * e2[j];
        blk = s + bn[b * 16 + k];
    } else {
        const float* wb = Wbe + k * 64;
        float s = 0.f;
        for (int j = 0; j < 32; ++j) s += wb[j] * eg1[j];
        for (int j = 0; j < 32; ++j) s += wb[32 + j] * eg2[j];
        blk = s + be[k];
    }
    float v = scoring[b * 16 + k] + blk;
    sval[b][k] = v > 0.f ? v : 0.f;
    __syncthreads();

    if (t < 4) {
        float h1[16], h2[8], h3[4];
        for (int o = 0; o < 16; ++o) {
            float a = m1b[t * 16 + o];
            for (int i = 0; i < 16; ++i) a += m1w[(t * 16 + o) * 16 + i] * sval[t][i];
            h1[o] = a > 0.f ? a : 0.f;
        }
        for (int o = 0; o < 8; ++o) {
            float a = m2b[t * 8 + o];
            for (int i = 0; i < 16; ++i) a += m2w[(t * 8 + o) * 16 + i] * h1[i];
            h2[o] = a > 0.f ? a : 0.f;
        }
        for (int o = 0; o < 4; ++o) {
            float a = m3b[t * 4 + o];
            for (int i = 0; i < 8; ++i) a += m3w[(t * 4 + o) * 8 + i] * h2[i];
            h3[o] = a > 0.f ? a : 0.f;
        }
        float z = sb[t];
        for (int i = 0; i < 4; ++i) z += sw[t * 4 + i] * h3[i];
        scores[t] = 1.0f / (1.0f + expf(-z));
    }
    __syncthreads();

    if (t == 0) {
        const int ord[4] = {0, 1, 3, 2};
        float av = avg_v[0];
        float acc = 0.f;
        for (int j = 0; j < 4; ++j) {
            float sc = scores[ord[j]];
            out[2 + j] = sc;
            acc += -logf(sc);
        }
        float ged = acc * av;
        out[1] = ged;
        out[0] = expf(-ged / av);
    }
}

extern "C" void kernel_launch(void* const* d_in, const int* in_sizes, int n_in,
                              void* d_out, int out_size, void* d_ws, size_t ws_size,
                              hipStream_t stream) {
    const float* emb1  = (const float*)d_in[0];
    const float* emb2  = (const float*)d_in[1];
    const float* adj1  = (const float*)d_in[2];
    const float* adj2  = (const float*)d_in[3];
    const float* eat1  = (const float*)d_in[4];
    const float* eat2  = (const float*)d_in[5];
    const float* eadj1 = (const float*)d_in[6];
    const float* eadj2 = (const float*)d_in[7];
    const float* avg_v = (const float*)d_in[8];
    const float* Wn    = (const float*)d_in[9];
    const float* Wbn   = (const float*)d_in[10];
    const float* bn    = (const float*)d_in[11];
    const float* We    = (const float*)d_in[12];
    const float* Wbe   = (const float*)d_in[13];
    const float* be    = (const float*)d_in[14];
    const float* m1w   = (const float*)d_in[15];
    const float* m1b   = (const float*)d_in[16];
    const float* m2w   = (const float*)d_in[17];
    const float* m2b   = (const float*)d_in[18];
    const float* m3w   = (const float*)d_in[19];
    const float* m3b   = (const float*)d_in[20];
    const float* sw    = (const float*)d_in[21];
    const float* sb    = (const float*)d_in[22];

    int Nn = in_sizes[0] / 32;   // 6000
    int Ne = in_sizes[4] / 16;   // 6000
    int N  = Nn;

    int strips = (N + TI - 1) / TI;          // 94
    int eSlabs = (N + EDGE_R - 1) / EDGE_R;  // 94

    size_t pFloats = (size_t)2 * strips * LDP;   // Pc / edge partials (shared, sequential)
    // pick largest nch in {8,4,2,1} that fits
    int nch = 8;
    while (nch > 1) {
        size_t need = (pFloats + (size_t)2 * nch * N * 32 + 4 * (size_t)N + 512) * 4;
        if (need <= ws_size) break;
        nch >>= 1;
    }
    int chunkW = (((N + nch - 1) / nch) + TJ - 1) & ~(TJ - 1);   // multiple of 64

    float* ws  = (float*)d_ws;
    float* P   = ws;
    float* PH  = P + pFloats;                     // [2][nch][N][32]
    float* c1  = PH + (size_t)2 * nch * N * 32;
    float* c2  = c1 + N;
    float* ce1 = c2 + N;
    float* ce2 = ce1 + N;
    float* n1  = ce2 + N;      // [s(32), p(32), q(32)]
    float* n2  = n1 + 96;
    float* eg1 = n2 + 96;      // [s(16), p(16)]
    float* eg2 = eg1 + 32;
    float* scoring = eg2 + 32; // [4][16]
    hipMemsetAsync(c1, 0, (4 * (size_t)N + 320) * sizeof(float), stream);

    dim3 blk(THREADS);
    int colChunks = (N + THREADS * 4 - 1) / (THREADS * 4);   // 6

    // 1) fused node pass: colsum partials + H1 partials, ONE read of adj1+adj2
    node_pass_kernel<<<dim3(nch, strips, 2), blk, 0, stream>>>(
        adj1, adj2, emb1, emb2, P, PH, N, strips, chunkW, nch);
    // 2) reduce node colsums -> c1, c2
    reduce_atomic_kernel<<<dim3(colChunks, 2, RGROUPS), blk, 0, stream>>>(P, c1, c2, N, strips);
    // 3) edge colsums (reuse P)
    colsum_tile_kernel<<<dim3(colChunks, eSlabs, 2), blk, 0, stream>>>(eadj1, eadj2, P, N, eSlabs, EDGE_R);
    // 4) reduce edge colsums -> ce1, ce2
    reduce_atomic_kernel<<<dim3(colChunks, 2, RGROUPS), blk, 0, stream>>>(P, ce1, ce2, N, eSlabs);
    // 5) tiny pooled-vector reductions (incl. q = c^T H1 over PH chunks)
    feat_all_kernel<<<dim3(16, 6), blk, 0, stream>>>(emb1, emb2, eat1, eat2, PH,
                                                     c1, c2, ce1, ce2,
                                                     n1, n2, eg1, eg2, Nn, Ne, nch);
    // 6) bilinear scoring
    scoring_kernel<<<dim3(16, 4), blk, 0, stream>>>(Wn, We, n1, n2, eg1, eg2, scoring);
    // 7) MLP head
    final_kernel<<<1, 64, 0, stream>>>(scoring, n1, n2, eg1, eg2,
                                       Wbn, bn, Wbe, be,
                                       m1w, m1b, m2w, m2b, m3w, m3b, sw, sb,
                                       avg_v, (float*)d_out);
}

// Round 10
// 257.589 us; speedup vs baseline: 1.4956x; 1.4956x over previous
//
#include <hip/hip_runtime.h>
#include <cstdint>
#include <cmath>

#define THREADS 256
#define LDP 6016
#define RGROUPS 8
#define EDGE_R 64        // edge colsum rows per slab -> 94 slabs
#define TI 64            // node rows per strip
#define TJ 64            // node cols per tile
#define ASTR 68          // A-tile stride (floats)
#define ESTR 36          // emb-tile stride
#define CSTR 68          // colsum buf stride
#define BSTR 36          // epilogue buf stride

// ---------------- fused node pass: Pc = colsum partials, PH = partial A*emb ----
__global__ void node_pass_kernel(const float* __restrict__ A0, const float* __restrict__ A1,
                                 const float* __restrict__ E0, const float* __restrict__ E1,
                                 float* __restrict__ Pc,   // [2][strips][LDP]
                                 float* __restrict__ PH,   // [2][nch][N][32]
                                 int N, int strips, int chunkW, int nch) {
    const int z = blockIdx.z;
    const float* __restrict__ A = z ? A1 : A0;
    const float* __restrict__ E = z ? E1 : E0;
    const int strip = blockIdx.y;
    const int r0 = strip * TI;
    const int rows = min(TI, N - r0);
    const int chunk = blockIdx.x;
    const int j0c = chunk * chunkW;
    const int j1c = min(j0c + chunkW, N);

    __shared__ float At[TI * ASTR];
    __shared__ float Et[TJ * ESTR];
    __shared__ float cs[16 * CSTR];

    const int t = threadIdx.x;
    const int rg = t & 15;
    const int lg = (t >> 4) & 3;
    const int jg = t >> 6;

    float acc[4][8];
#pragma unroll
    for (int k = 0; k < 4; ++k)
#pragma unroll
        for (int u = 0; u < 8; ++u) acc[k][u] = 0.f;

    const int sr = t >> 4;
    const int sc4 = t & 15;

    for (int jt = j0c; jt < j1c; jt += TJ) {
        float csx = 0.f, csy = 0.f, csz = 0.f, csw = 0.f;
#pragma unroll
        for (int p = 0; p < 4; ++p) {
            int r = sr + 16 * p;
            int gj = jt + 4 * sc4;
            float4 v = {0.f, 0.f, 0.f, 0.f};
            if (r < rows && gj < j1c)
                v = *reinterpret_cast<const float4*>(&A[(size_t)(r0 + r) * N + gj]);
            *reinterpret_cast<float4*>(&At[r * ASTR + 4 * sc4]) = v;
            csx += v.x; csy += v.y; csz += v.z; csw += v.w;
        }
        {
            float4 c4v = {csx, csy, csz, csw};
            *reinterpret_cast<float4*>(&cs[sr * CSTR + 4 * sc4]) = c4v;
        }
#pragma unroll
        for (int p = 0; p < 2; ++p) {
            int f = t + p * THREADS;
            int jr = f >> 3;
            int l4 = (f & 7) << 2;
            int gj = jt + jr;
            float4 v = {0.f, 0.f, 0.f, 0.f};
            if (gj < j1c)
                v = *reinterpret_cast<const float4*>(&E[(size_t)gj * 32 + l4]);
            *reinterpret_cast<float4*>(&Et[jr * ESTR + l4]) = v;
        }
        __syncthreads();

#pragma unroll 4
        for (int jj = 0; jj < 16; ++jj) {
            const int jl = jg * 16 + jj;
            const float a0 = At[(rg +  0) * ASTR + jl];
            const float a1 = At[(rg + 16) * ASTR + jl];
            const float a2 = At[(rg + 32) * ASTR + jl];
            const float a3 = At[(rg + 48) * ASTR + jl];
            const float4 eA = *reinterpret_cast<const float4*>(&Et[jl * ESTR + 8 * lg]);
            const float4 eB = *reinterpret_cast<const float4*>(&Et[jl * ESTR + 8 * lg + 4]);
            const float e[8] = {eA.x, eA.y, eA.z, eA.w, eB.x, eB.y, eB.z, eB.w};
#pragma unroll
            for (int u = 0; u < 8; ++u) {
                acc[0][u] += a0 * e[u];
                acc[1][u] += a1 * e[u];
                acc[2][u] += a2 * e[u];
                acc[3][u] += a3 * e[u];
            }
        }
        if (t < 64) {
            int gj = jt + t;
            if (gj < j1c) {
                float s = 0.f;
#pragma unroll
                for (int g = 0; g < 16; ++g) s += cs[g * CSTR + t];
                Pc[((size_t)z * strips + strip) * LDP + gj] = s;
            }
        }
        __syncthreads();
    }

    float* buf = At;
    for (int s = 0; s < 4; ++s) {
        if (jg == s) {
#pragma unroll
            for (int k = 0; k < 4; ++k) {
                float* b = &buf[(rg + 16 * k) * BSTR + 8 * lg];
                if (s == 0) {
#pragma unroll
                    for (int u = 0; u < 8; ++u) b[u] = acc[k][u];
                } else {
#pragma unroll
                    for (int u = 0; u < 8; ++u) b[u] += acc[k][u];
                }
            }
        }
        __syncthreads();
    }
    {
        int rr = t >> 2;
        int l8 = (t & 3) * 8;
        if (rr < rows) {
            const float* b = &buf[rr * BSTR + l8];
            float4 v0 = {b[0], b[1], b[2], b[3]};
            float4 v1 = {b[4], b[5], b[6], b[7]};
            size_t off = ((size_t)(z * nch + chunk) * N + (r0 + rr)) * 32 + l8;
            *reinterpret_cast<float4*>(&PH[off]) = v0;
            *reinterpret_cast<float4*>(&PH[off + 4]) = v1;
        }
    }
}

// ---------------- edge colsum (proven R6 structure) ----------------
__global__ __launch_bounds__(THREADS, 8)
void colsum_tile_kernel(const float* __restrict__ A0,
                        const float* __restrict__ A1,
                        float* __restrict__ P,
                        int N, int nSlabs, int R) {
    const int z = blockIdx.z;
    const float* __restrict__ A = z ? A1 : A0;
    const int col = blockIdx.x * (THREADS * 4) + threadIdx.x * 4;
    if (col >= N) return;
    const int slab = blockIdx.y;
    int r0 = slab * R;
    int r1 = r0 + R;
    if (r1 > N) r1 = N;

    float ax = 0.f, ay = 0.f, az = 0.f, aw = 0.f;
    float bx = 0.f, by = 0.f, bz = 0.f, bw = 0.f;
    const float* p = A + (size_t)r0 * N + col;
    const size_t sN = (size_t)N;
    int r = r0;
    for (; r + 8 <= r1; r += 8, p += 8 * sN) {
        float4 v0 = *reinterpret_cast<const float4*>(p + 0 * sN);
        float4 v1 = *reinterpret_cast<const float4*>(p + 1 * sN);
        float4 v2 = *reinterpret_cast<const float4*>(p + 2 * sN);
        float4 v3 = *reinterpret_cast<const float4*>(p + 3 * sN);
        float4 v4 = *reinterpret_cast<const float4*>(p + 4 * sN);
        float4 v5 = *reinterpret_cast<const float4*>(p + 5 * sN);
        float4 v6 = *reinterpret_cast<const float4*>(p + 6 * sN);
        float4 v7 = *reinterpret_cast<const float4*>(p + 7 * sN);
        ax += v0.x; ay += v0.y; az += v0.z; aw += v0.w;
        bx += v1.x; by += v1.y; bz += v1.z; bw += v1.w;
        ax += v2.x; ay += v2.y; az += v2.z; aw += v2.w;
        bx += v3.x; by += v3.y; bz += v3.z; bw += v3.w;
        ax += v4.x; ay += v4.y; az += v4.z; aw += v4.w;
        bx += v5.x; by += v5.y; bz += v5.z; bw += v5.w;
        ax += v6.x; ay += v6.y; az += v6.z; aw += v6.w;
        bx += v7.x; by += v7.y; bz += v7.z; bw += v7.w;
    }
    for (; r < r1; ++r, p += sN) {
        float4 v = *reinterpret_cast<const float4*>(p);
        ax += v.x; ay += v.y; az += v.z; aw += v.w;
    }
    float4 o = {ax + bx, ay + by, az + bz, aw + bw};
    *reinterpret_cast<float4*>(&P[((size_t)z * nSlabs + slab) * LDP + col]) = o;
}

// ---------------- reduce partials over slabs/strips ----------------
__global__ void reduce_atomic_kernel(const float* __restrict__ P,
                                     float* __restrict__ out0,
                                     float* __restrict__ out1,
                                     int N, int nSlabs) {
    int col = blockIdx.x * (THREADS * 4) + threadIdx.x * 4;
    if (col >= N) return;
    int z = blockIdx.y;
    int chunk = (nSlabs + RGROUPS - 1) / RGROUPS;
    int i0 = blockIdx.z * chunk;
    int i1 = i0 + chunk;
    if (i1 > nSlabs) i1 = nSlabs;
    float* out = z ? out1 : out0;

    const float* p = P + ((size_t)z * nSlabs + i0) * LDP + col;
    float4 s0 = {0, 0, 0, 0}, s1 = {0, 0, 0, 0};
    int i = i0;
    for (; i + 2 <= i1; i += 2, p += 2 * LDP) {
        float4 a = *reinterpret_cast<const float4*>(p);
        float4 b = *reinterpret_cast<const float4*>(p + LDP);
        s0.x += a.x; s0.y += a.y; s0.z += a.z; s0.w += a.w;
        s1.x += b.x; s1.y += b.y; s1.z += b.z; s1.w += b.w;
    }
    if (i < i1) {
        float4 a = *reinterpret_cast<const float4*>(p);
        s0.x += a.x; s0.y += a.y; s0.z += a.z; s0.w += a.w;
    }
    atomicAdd(&out[col + 0], s0.x + s1.x);
    atomicAdd(&out[col + 1], s0.y + s1.y);
    atomicAdd(&out[col + 2], s0.z + s1.z);
    atomicAdd(&out[col + 3], s0.w + s1.w);
}

// ---------------- merged tiny feature reductions (6 units) ----------------
// IDENTICAL to the R8-passing kernel except NCH is now a template parameter,
// so the unit-4/5 chunk loop fully unrolls into independent loads.
template <int NCH>
__global__ void feat_all_kernel(const float* __restrict__ emb1, const float* __restrict__ emb2,
                                const float* __restrict__ eat1, const float* __restrict__ eat2,
                                const float* __restrict__ PH,
                                const float* __restrict__ c1, const float* __restrict__ c2,
                                const float* __restrict__ ce1, const float* __restrict__ ce2,
                                float* __restrict__ n1, float* __restrict__ n2,
                                float* __restrict__ eg1, float* __restrict__ eg2,
                                int Nn, int Ne) {
    int unit = blockIdx.y;
    const float* feat = nullptr; const float* w = nullptr; const float* ph = nullptr;
    float* outS = nullptr; float* outP = nullptr;
    int total, log2L;
    if (unit == 0)      { feat = emb1; w = c1;  outS = n1;  outP = n1 + 32;  total = Nn * 32; log2L = 5; }
    else if (unit == 1) { feat = emb2; w = c2;  outS = n2;  outP = n2 + 32;  total = Nn * 32; log2L = 5; }
    else if (unit == 2) { feat = eat1; w = ce1; outS = eg1; outP = eg1 + 16; total = Ne * 16; log2L = 4; }
    else if (unit == 3) { feat = eat2; w = ce2; outS = eg2; outP = eg2 + 16; total = Ne * 16; log2L = 4; }
    else if (unit == 4) { ph = PH;                              w = c1; outP = n1 + 64; total = Nn * 32; log2L = 5; }
    else                { ph = PH + (size_t)NCH * Nn * 32;      w = c2; outP = n2 + 64; total = Nn * 32; log2L = 5; }

    int stride = gridDim.x * blockDim.x;
    int idx = blockIdx.x * blockDim.x + threadIdx.x;
    int L = 1 << log2L;
    int l = idx & (L - 1);
    float as = 0.f, ap = 0.f;
    if (ph) {
        for (int i = idx; i < total; i += stride) {
            float v = 0.f;
#pragma unroll
            for (int ch = 0; ch < NCH; ++ch) v += ph[(size_t)ch * total + i];
            ap += w[i >> log2L] * v;
        }
    } else {
        for (int i = idx; i < total; i += stride) {
            float v = feat[i];
            as += v;
            ap += w[i >> log2L] * v;
        }
        atomicAdd(&outS[l], as);
    }
    atomicAdd(&outP[l], ap);
}

// ---------------- scoring ----------------
__global__ void scoring_kernel(const float* __restrict__ Wn,
                               const float* __restrict__ We,
                               const float* __restrict__ n1,
                               const float* __restrict__ n2,
                               const float* __restrict__ eg1,
                               const float* __restrict__ eg2,
                               float* __restrict__ scoring) {
    int b = blockIdx.y;
    int chunk = blockIdx.x;
    const float *W, *e1, *e2;
    int total, log2D;
    if (b < 3) {
        W = Wn + (size_t)b * (64 * 64 * 16);
        e1 = n1 + (b == 2 ? 32 : 0);
        e2 = n2 + (b == 2 ? 32 : 0);
        total = 64 * 64 * 16;
        log2D = 6;
    } else {
        W = We; e1 = eg1; e2 = eg2;
        total = 32 * 32 * 16;
        log2D = 5;
    }
    int begin = chunk * 4096 + threadIdx.x;
    int end = (chunk + 1) * 4096;
    if (end > total) end = total;
    float acc = 0.f;
    for (int idx = begin; idx < end; idx += 256) {
        int de = idx >> 4;
        int e = de & ((1 << log2D) - 1);
        int dd = de >> log2D;
        acc += e1[dd] * e2[e] * W[idx];
    }
    __shared__ float red[256];
    red[threadIdx.x] = acc;
    __syncthreads();
    if (threadIdx.x < 16) {
        float s = 0.f;
        for (int t = threadIdx.x; t < 256; t += 16) s += red[t];
        atomicAdd(&scoring[b * 16 + threadIdx.x], s);
    }
}

// ---------------- final MLP head ----------------
__global__ void final_kernel(const float* __restrict__ scoring,
                             const float* __restrict__ n1,
                             const float* __restrict__ n2,
                             const float* __restrict__ eg1,
                             const float* __restrict__ eg2,
                             const float* __restrict__ Wbn,
                             const float* __restrict__ bn,
                             const float* __restrict__ Wbe,
                             const float* __restrict__ be,
                             const float* __restrict__ m1w, const float* __restrict__ m1b,
                             const float* __restrict__ m2w, const float* __restrict__ m2b,
                             const float* __restrict__ m3w, const float* __restrict__ m3b,
                             const float* __restrict__ sw, const float* __restrict__ sb,
                             const float* __restrict__ avg_v,
                             float* __restrict__ out) {
    __shared__ float sval[4][16];
    __shared__ float scores[4];
    int t = threadIdx.x;
    int b = t >> 4, k = t & 15;

    float blk;
    if (b < 3) {
        const float* e1 = n1 + (b == 2 ? 32 : 0);
        const float* e2 = n2 + (b == 2 ? 32 : 0);
        const float* wb = Wbn + (size_t)b * (16 * 128) + k * 128;
        float s = 0.f;
        for (int j = 0; j < 64; ++j) s += wb[j] * e1[j];
        for (int j = 0; j < 64; ++j) s += wb[64 + j] * e2[j];
        blk = s + bn[b * 16 + k];
    } else {
        const float* wb = Wbe + k * 64;
        float s = 0.f;
        for (int j = 0; j < 32; ++j) s += wb[j] * eg1[j];
        for (int j = 0; j < 32; ++j) s += wb[32 + j] * eg2[j];
        blk = s + be[k];
    }
    float v = scoring[b * 16 + k] + blk;
    sval[b][k] = v > 0.f ? v : 0.f;
    __syncthreads();

    if (t < 4) {
        float h1[16], h2[8], h3[4];
        for (int o = 0; o < 16; ++o) {
            float a = m1b[t * 16 + o];
            for (int i = 0; i < 16; ++i) a += m1w[(t * 16 + o) * 16 + i] * sval[t][i];
            h1[o] = a > 0.f ? a : 0.f;
        }
        for (int o = 0; o < 8; ++o) {
            float a = m2b[t * 8 + o];
            for (int i = 0; i < 16; ++i) a += m2w[(t * 8 + o) * 16 + i] * h1[i];
            h2[o] = a > 0.f ? a : 0.f;
        }
        for (int o = 0; o < 4; ++o) {
            float a = m3b[t * 4 + o];
            for (int i = 0; i < 8; ++i) a += m3w[(t * 4 + o) * 8 + i] * h2[i];
            h3[o] = a > 0.f ? a : 0.f;
        }
        float z = sb[t];
        for (int i = 0; i < 4; ++i) z += sw[t * 4 + i] * h3[i];
        scores[t] = 1.0f / (1.0f + expf(-z));
    }
    __syncthreads();

    if (t == 0) {
        const int ord[4] = {0, 1, 3, 2};
        float av = avg_v[0];
        float acc = 0.f;
        for (int j = 0; j < 4; ++j) {
            float sc = scores[ord[j]];
            out[2 + j] = sc;
            acc += -logf(sc);
        }
        float ged = acc * av;
        out[1] = ged;
        out[0] = expf(-ged / av);
    }
}

extern "C" void kernel_launch(void* const* d_in, const int* in_sizes, int n_in,
                              void* d_out, int out_size, void* d_ws, size_t ws_size,
                              hipStream_t stream) {
    const float* emb1  = (const float*)d_in[0];
    const float* emb2  = (const float*)d_in[1];
    const float* adj1  = (const float*)d_in[2];
    const float* adj2  = (const float*)d_in[3];
    const float* eat1  = (const float*)d_in[4];
    const float* eat2  = (const float*)d_in[5];
    const float* eadj1 = (const float*)d_in[6];
    const float* eadj2 = (const float*)d_in[7];
    const float* avg_v = (const float*)d_in[8];
    const float* Wn    = (const float*)d_in[9];
    const float* Wbn   = (const float*)d_in[10];
    const float* bn    = (const float*)d_in[11];
    const float* We    = (const float*)d_in[12];
    const float* Wbe   = (const float*)d_in[13];
    const float* be    = (const float*)d_in[14];
    const float* m1w   = (const float*)d_in[15];
    const float* m1b   = (const float*)d_in[16];
    const float* m2w   = (const float*)d_in[17];
    const float* m2b   = (const float*)d_in[18];
    const float* m3w   = (const float*)d_in[19];
    const float* m3b   = (const float*)d_in[20];
    const float* sw    = (const float*)d_in[21];
    const float* sb    = (const float*)d_in[22];

    int Nn = in_sizes[0] / 32;   // 6000
    int Ne = in_sizes[4] / 16;   // 6000
    int N  = Nn;

    int strips = (N + TI - 1) / TI;          // 94
    int eSlabs = (N + EDGE_R - 1) / EDGE_R;  // 94

    size_t pFloats = (size_t)2 * strips * LDP;
    int nch = 8;
    while (nch > 1) {
        size_t need = (pFloats + (size_t)2 * nch * N * 32 + 4 * (size_t)N + 512) * 4;
        if (need <= ws_size) break;
        nch >>= 1;
    }
    int chunkW = (((N + nch - 1) / nch) + TJ - 1) & ~(TJ - 1);

    float* ws  = (float*)d_ws;
    float* P   = ws;
    float* PH  = P + pFloats;                     // [2][nch][N][32]
    float* c1  = PH + (size_t)2 * nch * N * 32;
    float* c2  = c1 + N;
    float* ce1 = c2 + N;
    float* ce2 = ce1 + N;
    float* n1  = ce2 + N;      // [s(32), p(32), q(32)]
    float* n2  = n1 + 96;
    float* eg1 = n2 + 96;      // [s(16), p(16)]
    float* eg2 = eg1 + 32;
    float* scoring = eg2 + 32; // [4][16]
    hipMemsetAsync(c1, 0, (4 * (size_t)N + 320) * sizeof(float), stream);

    dim3 blk(THREADS);
    int colChunks = (N + THREADS * 4 - 1) / (THREADS * 4);   // 6

    // 1) fused node pass: colsum partials + H1 partials (one read of adj1+adj2)
    node_pass_kernel<<<dim3(nch, strips, 2), blk, 0, stream>>>(
        adj1, adj2, emb1, emb2, P, PH, N, strips, chunkW, nch);
    // 2) reduce node colsums -> c1, c2
    reduce_atomic_kernel<<<dim3(colChunks, 2, RGROUPS), blk, 0, stream>>>(P, c1, c2, N, strips);
    // 3) edge colsums (reuse P)
    colsum_tile_kernel<<<dim3(colChunks, eSlabs, 2), blk, 0, stream>>>(eadj1, eadj2, P, N, eSlabs, EDGE_R);
    // 4) reduce edge colsums -> ce1, ce2
    reduce_atomic_kernel<<<dim3(colChunks, 2, RGROUPS), blk, 0, stream>>>(P, ce1, ce2, N, eSlabs);
    // 5) tiny pooled-vector reductions (s, p for emb/eat; q = c^T sum_ch PH)
    if (nch == 8)
        feat_all_kernel<8><<<dim3(16, 6), blk, 0, stream>>>(emb1, emb2, eat1, eat2, PH,
                                                            c1, c2, ce1, ce2,
                                                            n1, n2, eg1, eg2, Nn, Ne);
    else if (nch == 4)
        feat_all_kernel<4><<<dim3(16, 6), blk, 0, stream>>>(emb1, emb2, eat1, eat2, PH,
                                                            c1, c2, ce1, ce2,
                                                            n1, n2, eg1, eg2, Nn, Ne);
    else if (nch == 2)
        feat_all_kernel<2><<<dim3(16, 6), blk, 0, stream>>>(emb1, emb2, eat1, eat2, PH,
                                                            c1, c2, ce1, ce2,
                                                            n1, n2, eg1, eg2, Nn, Ne);
    else
        feat_all_kernel<1><<<dim3(16, 6), blk, 0, stream>>>(emb1, emb2, eat1, eat2, PH,
                                                            c1, c2, ce1, ce2,
                                                            n1, n2, eg1, eg2, Nn, Ne);
    // 6) bilinear scoring
    scoring_kernel<<<dim3(16, 4), blk, 0, stream>>>(Wn, We, n1, n2, eg1, eg2, scoring);
    // 7) MLP head
    final_kernel<<<1, 64, 0, stream>>>(scoring, n1, n2, eg1, eg2,
                                       Wbn, bn, Wbe, be,
                                       m1w, m1b, m2w, m2b, m3w, m3b, sw, sb,
                                       avg_v, (float*)d_out);
}

// Round 11
// 208.768 us; speedup vs baseline: 1.8453x; 1.2338x over previous
//
#include <hip/hip_runtime.h>
#include <cstdint>
#include <cmath>

#define THREADS 256
#define LDP 6016
#define RGROUPS 8
#define SLAB_R 64        // rows per slab -> 94 slabs

typedef float vf4 __attribute__((ext_vector_type(4)));

// ---------------- unweighted colsum over FOUR matrices ----------------
// z: 0=eadj1(nt), 1=eadj2(nt), 2=adj1, 3=adj2. nt keeps single-use edge data
// out of L3 so adj stays resident for the weighted pass.
__global__ __launch_bounds__(THREADS, 8)
void colsum4_kernel(const float* __restrict__ M0, const float* __restrict__ M1,
                    const float* __restrict__ M2, const float* __restrict__ M3,
                    float* __restrict__ P, int N, int nSlabs, int R) {
    const int z = blockIdx.z;
    const float* __restrict__ A = (z == 0) ? M0 : (z == 1) ? M1 : (z == 2) ? M2 : M3;
    const int col = blockIdx.x * (THREADS * 4) + threadIdx.x * 4;
    if (col >= N) return;
    const int slab = blockIdx.y;
    int r0 = slab * R;
    int r1 = r0 + R;
    if (r1 > N) r1 = N;

    float ax = 0.f, ay = 0.f, az = 0.f, aw = 0.f;
    float bx = 0.f, by = 0.f, bz = 0.f, bw = 0.f;
    const float* p = A + (size_t)r0 * N + col;
    const size_t sN = (size_t)N;
    int r = r0;
    if (z < 2) {
        for (; r + 8 <= r1; r += 8, p += 8 * sN) {
            vf4 v0 = __builtin_nontemporal_load((const vf4*)(p + 0 * sN));
            vf4 v1 = __builtin_nontemporal_load((const vf4*)(p + 1 * sN));
            vf4 v2 = __builtin_nontemporal_load((const vf4*)(p + 2 * sN));
            vf4 v3 = __builtin_nontemporal_load((const vf4*)(p + 3 * sN));
            vf4 v4 = __builtin_nontemporal_load((const vf4*)(p + 4 * sN));
            vf4 v5 = __builtin_nontemporal_load((const vf4*)(p + 5 * sN));
            vf4 v6 = __builtin_nontemporal_load((const vf4*)(p + 6 * sN));
            vf4 v7 = __builtin_nontemporal_load((const vf4*)(p + 7 * sN));
            ax += v0.x; ay += v0.y; az += v0.z; aw += v0.w;
            bx += v1.x; by += v1.y; bz += v1.z; bw += v1.w;
            ax += v2.x; ay += v2.y; az += v2.z; aw += v2.w;
            bx += v3.x; by += v3.y; bz += v3.z; bw += v3.w;
            ax += v4.x; ay += v4.y; az += v4.z; aw += v4.w;
            bx += v5.x; by += v5.y; bz += v5.z; bw += v5.w;
            ax += v6.x; ay += v6.y; az += v6.z; aw += v6.w;
            bx += v7.x; by += v7.y; bz += v7.z; bw += v7.w;
        }
    } else {
        for (; r + 8 <= r1; r += 8, p += 8 * sN) {
            vf4 v0 = *(const vf4*)(p + 0 * sN);
            vf4 v1 = *(const vf4*)(p + 1 * sN);
            vf4 v2 = *(const vf4*)(p + 2 * sN);
            vf4 v3 = *(const vf4*)(p + 3 * sN);
            vf4 v4 = *(const vf4*)(p + 4 * sN);
            vf4 v5 = *(const vf4*)(p + 5 * sN);
            vf4 v6 = *(const vf4*)(p + 6 * sN);
            vf4 v7 = *(const vf4*)(p + 7 * sN);
            ax += v0.x; ay += v0.y; az += v0.z; aw += v0.w;
            bx += v1.x; by += v1.y; bz += v1.z; bw += v1.w;
            ax += v2.x; ay += v2.y; az += v2.z; aw += v2.w;
            bx += v3.x; by += v3.y; bz += v3.z; bw += v3.w;
            ax += v4.x; ay += v4.y; az += v4.z; aw += v4.w;
            bx += v5.x; by += v5.y; bz += v5.z; bw += v5.w;
            ax += v6.x; ay += v6.y; az += v6.z; aw += v6.w;
            bx += v7.x; by += v7.y; bz += v7.z; bw += v7.w;
        }
    }
    for (; r < r1; ++r, p += sN) {
        vf4 v = *(const vf4*)(p);
        ax += v.x; ay += v.y; az += v.z; aw += v.w;
    }
    float4 o = {ax + bx, ay + by, az + bz, aw + bw};
    *reinterpret_cast<float4*>(&P[((size_t)z * nSlabs + slab) * LDP + col]) = o;
}

// ---------------- weighted colsum over TWO matrices (d = A^T c) --------------
__global__ __launch_bounds__(THREADS, 8)
void colsum2w_kernel(const float* __restrict__ A0, const float* __restrict__ A1,
                     const float* __restrict__ w0, const float* __restrict__ w1,
                     float* __restrict__ P, int N, int nSlabs, int R) {
    const int z = blockIdx.z;
    const float* __restrict__ A = z ? A1 : A0;
    const float* __restrict__ wv = z ? w1 : w0;
    const int col = blockIdx.x * (THREADS * 4) + threadIdx.x * 4;
    if (col >= N) return;
    const int slab = blockIdx.y;
    int r0 = slab * R;
    int r1 = r0 + R;
    if (r1 > N) r1 = N;

    float ax = 0.f, ay = 0.f, az = 0.f, aw = 0.f;
    float bx = 0.f, by = 0.f, bz = 0.f, bw = 0.f;
    const float* p = A + (size_t)r0 * N + col;
    const size_t sN = (size_t)N;
    int r = r0;
    for (; r + 8 <= r1; r += 8, p += 8 * sN) {
        vf4 v0 = *(const vf4*)(p + 0 * sN);
        vf4 v1 = *(const vf4*)(p + 1 * sN);
        vf4 v2 = *(const vf4*)(p + 2 * sN);
        vf4 v3 = *(const vf4*)(p + 3 * sN);
        vf4 v4 = *(const vf4*)(p + 4 * sN);
        vf4 v5 = *(const vf4*)(p + 5 * sN);
        vf4 v6 = *(const vf4*)(p + 6 * sN);
        vf4 v7 = *(const vf4*)(p + 7 * sN);
        float q0 = wv[r + 0], q1 = wv[r + 1], q2 = wv[r + 2], q3 = wv[r + 3];
        float q4 = wv[r + 4], q5 = wv[r + 5], q6 = wv[r + 6], q7 = wv[r + 7];
        ax += q0 * v0.x; ay += q0 * v0.y; az += q0 * v0.z; aw += q0 * v0.w;
        bx += q1 * v1.x; by += q1 * v1.y; bz += q1 * v1.z; bw += q1 * v1.w;
        ax += q2 * v2.x; ay += q2 * v2.y; az += q2 * v2.z; aw += q2 * v2.w;
        bx += q3 * v3.x; by += q3 * v3.y; bz += q3 * v3.z; bw += q3 * v3.w;
        ax += q4 * v4.x; ay += q4 * v4.y; az += q4 * v4.z; aw += q4 * v4.w;
        bx += q5 * v5.x; by += q5 * v5.y; bz += q5 * v5.z; bw += q5 * v5.w;
        ax += q6 * v6.x; ay += q6 * v6.y; az += q6 * v6.z; aw += q6 * v6.w;
        bx += q7 * v7.x; by += q7 * v7.y; bz += q7 * v7.z; bw += q7 * v7.w;
    }
    for (; r < r1; ++r, p += sN) {
        vf4 v = *(const vf4*)(p);
        float q = wv[r];
        ax += q * v.x; ay += q * v.y; az += q * v.z; aw += q * v.w;
    }
    float4 o = {ax + bx, ay + by, az + bz, aw + bw};
    *reinterpret_cast<float4*>(&P[((size_t)z * nSlabs + slab) * LDP + col]) = o;
}

// ---------------- reduce partials over slabs; out selected by z --------------
__global__ void reduce4_kernel(const float* __restrict__ P,
                               float* __restrict__ o0, float* __restrict__ o1,
                               float* __restrict__ o2, float* __restrict__ o3,
                               int N, int nSlabs) {
    int col = blockIdx.x * (THREADS * 4) + threadIdx.x * 4;
    if (col >= N) return;
    int z = blockIdx.y;
    float* out = (z == 0) ? o0 : (z == 1) ? o1 : (z == 2) ? o2 : o3;
    int chunk = (nSlabs + RGROUPS - 1) / RGROUPS;
    int i0 = blockIdx.z * chunk;
    int i1 = i0 + chunk;
    if (i1 > nSlabs) i1 = nSlabs;

    const float* p = P + ((size_t)z * nSlabs + i0) * LDP + col;
    float4 s0 = {0, 0, 0, 0}, s1 = {0, 0, 0, 0};
    int i = i0;
    for (; i + 2 <= i1; i += 2, p += 2 * LDP) {
        float4 a = *reinterpret_cast<const float4*>(p);
        float4 b = *reinterpret_cast<const float4*>(p + LDP);
        s0.x += a.x; s0.y += a.y; s0.z += a.z; s0.w += a.w;
        s1.x += b.x; s1.y += b.y; s1.z += b.z; s1.w += b.w;
    }
    if (i < i1) {
        float4 a = *reinterpret_cast<const float4*>(p);
        s0.x += a.x; s0.y += a.y; s0.z += a.z; s0.w += a.w;
    }
    atomicAdd(&out[col + 0], s0.x + s1.x);
    atomicAdd(&out[col + 1], s0.y + s1.y);
    atomicAdd(&out[col + 2], s0.z + s1.z);
    atomicAdd(&out[col + 3], s0.w + s1.w);
}

// ---------------- tiny feature reductions (4 units: s,p,q per input) ---------
// unit0: emb1 w/ c1,d1 -> n1[96]; unit1: emb2 w/ c2,d2 -> n2[96]
// unit2: eat1 w/ ce1 -> eg1[32];  unit3: eat2 w/ ce2 -> eg2[32]
__global__ void feat_all_kernel(const float* __restrict__ emb1, const float* __restrict__ emb2,
                                const float* __restrict__ eat1, const float* __restrict__ eat2,
                                const float* __restrict__ c1, const float* __restrict__ d1,
                                const float* __restrict__ c2, const float* __restrict__ d2,
                                const float* __restrict__ ce1, const float* __restrict__ ce2,
                                float* __restrict__ n1, float* __restrict__ n2,
                                float* __restrict__ eg1, float* __restrict__ eg2,
                                int Nn, int Ne) {
    int unit = blockIdx.y;
    const float *feat, *c, *d;
    float* out;
    int total, log2L;
    bool hasQ;
    if (unit == 0)      { feat = emb1; c = c1;  d = d1;      out = n1;  total = Nn * 32; log2L = 5; hasQ = true;  }
    else if (unit == 1) { feat = emb2; c = c2;  d = d2;      out = n2;  total = Nn * 32; log2L = 5; hasQ = true;  }
    else if (unit == 2) { feat = eat1; c = ce1; d = nullptr; out = eg1; total = Ne * 16; log2L = 4; hasQ = false; }
    else                { feat = eat2; c = ce2; d = nullptr; out = eg2; total = Ne * 16; log2L = 4; hasQ = false; }

    int stride = gridDim.x * blockDim.x;   // multiple of 32
    int idx = blockIdx.x * blockDim.x + threadIdx.x;
    int L = 1 << log2L;
    int l = idx & (L - 1);
    float as = 0.f, ap = 0.f, aq = 0.f;
    for (int i = idx; i < total; i += stride) {
        float v = feat[i];
        int r = i >> log2L;
        as += v;
        ap += c[r] * v;
        if (hasQ) aq += d[r] * v;
    }
    atomicAdd(&out[l], as);
    atomicAdd(&out[L + l], ap);
    if (hasQ) atomicAdd(&out[2 * L + l], aq);
}

// ---------------- scoring ----------------
__global__ void scoring_kernel(const float* __restrict__ Wn,
                               const float* __restrict__ We,
                               const float* __restrict__ n1,
                               const float* __restrict__ n2,
                               const float* __restrict__ eg1,
                               const float* __restrict__ eg2,
                               float* __restrict__ scoring) {
    int b = blockIdx.y;
    int chunk = blockIdx.x;
    const float *W, *e1, *e2;
    int total, log2D;
    if (b < 3) {
        W = Wn + (size_t)b * (64 * 64 * 16);
        e1 = n1 + (b == 2 ? 32 : 0);
        e2 = n2 + (b == 2 ? 32 : 0);
        total = 64 * 64 * 16;
        log2D = 6;
    } else {
        W = We; e1 = eg1; e2 = eg2;
        total = 32 * 32 * 16;
        log2D = 5;
    }
    int begin = chunk * 4096 + threadIdx.x;
    int end = (chunk + 1) * 4096;
    if (end > total) end = total;
    float acc = 0.f;
    for (int idx = begin; idx < end; idx += 256) {
        int de = idx >> 4;
        int e = de & ((1 << log2D) - 1);
        int dd = de >> log2D;
        acc += e1[dd] * e2[e] * W[idx];
    }
    __shared__ float red[256];
    red[threadIdx.x] = acc;
    __syncthreads();
    if (threadIdx.x < 16) {
        float s = 0.f;
        for (int t = threadIdx.x; t < 256; t += 16) s += red[t];
        atomicAdd(&scoring[b * 16 + threadIdx.x], s);
    }
}

// ---------------- final MLP head ----------------
__global__ void final_kernel(const float* __restrict__ scoring,
                             const float* __restrict__ n1,
                             const float* __restrict__ n2,
                             const float* __restrict__ eg1,
                             const float* __restrict__ eg2,
                             const float* __restrict__ Wbn,
                             const float* __restrict__ bn,
                             const float* __restrict__ Wbe,
                             const float* __restrict__ be,
                             const float* __restrict__ m1w, const float* __restrict__ m1b,
                             const float* __restrict__ m2w, const float* __restrict__ m2b,
                             const float* __restrict__ m3w, const float* __restrict__ m3b,
                             const float* __restrict__ sw, const float* __restrict__ sb,
                             const float* __restrict__ avg_v,
                             float* __restrict__ out) {
    __shared__ float sval[4][16];
    __shared__ float scores[4];
    int t = threadIdx.x;
    int b = t >> 4, k = t & 15;

    float blk;
    if (b < 3) {
        const float* e1 = n1 + (b == 2 ? 32 : 0);
        const float* e2 = n2 + (b == 2 ? 32 : 0);
        const float* wb = Wbn + (size_t)b * (16 * 128) + k * 128;
        float s = 0.f;
        for (int j = 0; j < 64; ++j) s += wb[j] * e1[j];
        for (int j = 0; j < 64; ++j) s += wb[64 + j] * e2[j];
        blk = s + bn[b * 16 + k];
    } else {
        const float* wb = Wbe + k * 64;
        float s = 0.f;
        for (int j = 0; j < 32; ++j) s += wb[j] * eg1[j];
        for (int j = 0; j < 32; ++j) s += wb[32 + j] * eg2[j];
        blk = s + be[k];
    }
    float v = scoring[b * 16 + k] + blk;
    sval[b][k] = v > 0.f ? v : 0.f;
    __syncthreads();

    if (t < 4) {
        float h1[16], h2[8], h3[4];
        for (int o = 0; o < 16; ++o) {
            float a = m1b[t * 16 + o];
            for (int i = 0; i < 16; ++i) a += m1w[(t * 16 + o) * 16 + i] * sval[t][i];
            h1[o] = a > 0.f ? a : 0.f;
        }
        for (int o = 0; o < 8; ++o) {
            float a = m2b[t * 8 + o];
            for (int i = 0; i < 16; ++i) a += m2w[(t * 8 + o) * 16 + i] * h1[i];
            h2[o] = a > 0.f ? a : 0.f;
        }
        for (int o = 0; o < 4; ++o) {
            float a = m3b[t * 4 + o];
            for (int i = 0; i < 8; ++i) a += m3w[(t * 4 + o) * 8 + i] * h2[i];
            h3[o] = a > 0.f ? a : 0.f;
        }
        float z = sb[t];
        for (int i = 0; i < 4; ++i) z += sw[t * 4 + i] * h3[i];
        scores[t] = 1.0f / (1.0f + expf(-z));
    }
    __syncthreads();

    if (t == 0) {
        const int ord[4] = {0, 1, 3, 2};
        float av = avg_v[0];
        float acc = 0.f;
        for (int j = 0; j < 4; ++j) {
            float sc = scores[ord[j]];
            out[2 + j] = sc;
            acc += -logf(sc);
        }
        float ged = acc * av;
        out[1] = ged;
        out[0] = expf(-ged / av);
    }
}

extern "C" void kernel_launch(void* const* d_in, const int* in_sizes, int n_in,
                              void* d_out, int out_size, void* d_ws, size_t ws_size,
                              hipStream_t stream) {
    const float* emb1  = (const float*)d_in[0];
    const float* emb2  = (const float*)d_in[1];
    const float* adj1  = (const float*)d_in[2];
    const float* adj2  = (const float*)d_in[3];
    const float* eat1  = (const float*)d_in[4];
    const float* eat2  = (const float*)d_in[5];
    const float* eadj1 = (const float*)d_in[6];
    const float* eadj2 = (const float*)d_in[7];
    const float* avg_v = (const float*)d_in[8];
    const float* Wn    = (const float*)d_in[9];
    const float* Wbn   = (const float*)d_in[10];
    const float* bn    = (const float*)d_in[11];
    const float* We    = (const float*)d_in[12];
    const float* Wbe   = (const float*)d_in[13];
    const float* be    = (const float*)d_in[14];
    const float* m1w   = (const float*)d_in[15];
    const float* m1b   = (const float*)d_in[16];
    const float* m2w   = (const float*)d_in[17];
    const float* m2b   = (const float*)d_in[18];
    const float* m3w   = (const float*)d_in[19];
    const float* m3b   = (const float*)d_in[20];
    const float* sw    = (const float*)d_in[21];
    const float* sb    = (const float*)d_in[22];

    int Nn = in_sizes[0] / 32;   // 6000
    int Ne = in_sizes[4] / 16;   // 6000
    int N  = Nn;

    int nSlabs = (N + SLAB_R - 1) / SLAB_R;    // 94

    float* ws  = (float*)d_ws;
    float* P   = ws;                            // [4][nSlabs][LDP]
    float* c1  = P + (size_t)4 * nSlabs * LDP;
    float* c2  = c1 + N;
    float* ce1 = c2 + N;
    float* ce2 = ce1 + N;
    float* d1  = ce2 + N;
    float* d2  = d1 + N;
    float* n1  = d2 + N;       // [s(32), p(32), q(32)]
    float* n2  = n1 + 96;
    float* eg1 = n2 + 96;      // [s(16), p(16)]
    float* eg2 = eg1 + 32;
    float* scoring = eg2 + 32; // [4][16]
    // zero all atomically-accumulated outputs: c1..d2 (6N) + tail (320)
    hipMemsetAsync(c1, 0, (6 * (size_t)N + 320) * sizeof(float), stream);

    dim3 blk(THREADS);
    int colChunks = (N + THREADS * 4 - 1) / (THREADS * 4);   // 6

    // 1) unweighted colsums of ALL FOUR matrices (eadj via nt loads -> L3 holds adj)
    colsum4_kernel<<<dim3(colChunks, nSlabs, 4), blk, 0, stream>>>(
        eadj1, eadj2, adj1, adj2, P, N, nSlabs, SLAB_R);
    // 2) reduce -> ce1, ce2, c1, c2
    reduce4_kernel<<<dim3(colChunks, 4, RGROUPS), blk, 0, stream>>>(
        P, ce1, ce2, c1, c2, N, nSlabs);
    // 3) weighted colsums d = A^T c (adj hopefully L3-resident)
    colsum2w_kernel<<<dim3(colChunks, nSlabs, 2), blk, 0, stream>>>(
        adj1, adj2, c1, c2, P, N, nSlabs, SLAB_R);
    // 4) reduce -> d1, d2
    reduce4_kernel<<<dim3(colChunks, 2, RGROUPS), blk, 0, stream>>>(
        P, d1, d2, d1, d2, N, nSlabs);
    // 5) pooled vectors: s, p = c^T feat, q = d^T feat
    feat_all_kernel<<<dim3(16, 4), blk, 0, stream>>>(emb1, emb2, eat1, eat2,
                                                     c1, d1, c2, d2, ce1, ce2,
                                                     n1, n2, eg1, eg2, Nn, Ne);
    // 6) bilinear scoring
    scoring_kernel<<<dim3(16, 4), blk, 0, stream>>>(Wn, We, n1, n2, eg1, eg2, scoring);
    // 7) MLP head
    final_kernel<<<1, 64, 0, stream>>>(scoring, n1, n2, eg1, eg2,
                                       Wbn, bn, Wbe, be,
                                       m1w, m1b, m2w, m2b, m3w, m3b, sw, sb,
                                       avg_v, (float*)d_out);
}